// Round 4
// baseline (1336.103 us; speedup 1.0000x reference)
//
#include <hip/hip_runtime.h>

typedef unsigned short u16;
typedef unsigned int u32;
typedef __attribute__((ext_vector_type(8))) short bf16x8;
typedef __attribute__((ext_vector_type(4))) float f32x4;

#define HW 65536

__device__ __forceinline__ float bf2f(u32 v) { return __uint_as_float(v << 16); }
__device__ __forceinline__ u16 f2bf(float f) {
  u32 u = __float_as_uint(f);
  u += 0x7fffu + ((u >> 16) & 1u);   // RNE; inputs are finite
  return (u16)(u >> 16);
}

__device__ __forceinline__ void unpack8(uint4 u, float r[8]) {
  r[0] = bf2f(u.x & 0xffffu); r[1] = bf2f(u.x >> 16);
  r[2] = bf2f(u.y & 0xffffu); r[3] = bf2f(u.y >> 16);
  r[4] = bf2f(u.z & 0xffffu); r[5] = bf2f(u.z >> 16);
  r[6] = bf2f(u.w & 0xffffu); r[7] = bf2f(u.w >> 16);
}

// ---------------- LayerNorm over channel dim (thread = 2 adjacent pixels) ----
template <int INF32>
__global__ __launch_bounds__(256)
void ln_k(const void* __restrict__ xv, const float* __restrict__ gw,
          const float* __restrict__ gb, u16* __restrict__ y, int C)
{
  int pi = blockIdx.x * 256 + threadIdx.x;
  int p2 = pi << 1;
  int b = p2 >> 16;
  int p = p2 & (HW - 1);
  const float* xf = (const float*)xv + (size_t)b * C * HW + p;
  const u16* xh = (const u16*)xv + (size_t)b * C * HW + p;
  u16* yb = y + (size_t)b * C * HW + p;
  float s0 = 0, s1 = 0, q0 = 0, q1 = 0;
  for (int c = 0; c < C; ++c) {
    float a, d;
    if (INF32) {
      float2 u = *(const float2*)(xf + (size_t)c * HW);
      a = u.x; d = u.y;
    } else {
      u32 u = *(const u32*)(xh + (size_t)c * HW);
      a = bf2f(u & 0xffffu); d = bf2f(u >> 16);
    }
    s0 += a; q0 += a * a; s1 += d; q1 += d * d;
  }
  float inv = 1.0f / (float)C;
  float m0 = s0 * inv, m1 = s1 * inv;
  float r0 = rsqrtf(fmaxf(q0 * inv - m0 * m0, 0.f) + 1e-6f);
  float r1 = rsqrtf(fmaxf(q1 * inv - m1 * m1, 0.f) + 1e-6f);
  for (int c = 0; c < C; ++c) {
    float a, d;
    if (INF32) {
      float2 u = *(const float2*)(xf + (size_t)c * HW);
      a = u.x; d = u.y;
    } else {
      u32 u = *(const u32*)(xh + (size_t)c * HW);
      a = bf2f(u & 0xffffu); d = bf2f(u >> 16);
    }
    float w = gw[c], bb = gb[c];
    a = (a - m0) * r0 * w + bb;
    d = (d - m1) * r1 * w + bb;
    *(u32*)(yb + (size_t)c * HW) = (u32)f2bf(a) | ((u32)f2bf(d) << 16);
  }
}

// ---------------- LN2 over 256 channels fused with v-multiply ---------------
__global__ __launch_bounds__(256)
void ln2v_k(u16* __restrict__ qkv, const float* __restrict__ gw,
            const float* __restrict__ gb)
{
  int pi = blockIdx.x * 256 + threadIdx.x;
  int p2 = pi << 1;
  int b = p2 >> 16;
  int p = p2 & (HW - 1);
  u16* ab = qkv + ((size_t)(b * 768) << 16) + p;               // attn (q-slot)
  const u16* vb = qkv + ((size_t)(b * 768 + 512) << 16) + p;   // v
  float s0 = 0, s1 = 0, q0 = 0, q1 = 0;
  for (int c = 0; c < 256; ++c) {
    u32 u = *(const u32*)(ab + (size_t)c * HW);
    float a = bf2f(u & 0xffffu), d = bf2f(u >> 16);
    s0 += a; q0 += a * a; s1 += d; q1 += d * d;
  }
  const float inv = 1.0f / 256.0f;
  float m0 = s0 * inv, m1 = s1 * inv;
  float r0 = rsqrtf(fmaxf(q0 * inv - m0 * m0, 0.f) + 1e-6f);
  float r1 = rsqrtf(fmaxf(q1 * inv - m1 * m1, 0.f) + 1e-6f);
  for (int c = 0; c < 256; ++c) {
    u32 u = *(const u32*)(ab + (size_t)c * HW);
    u32 vv = *(const u32*)(vb + (size_t)c * HW);
    float w = gw[c], bb = gb[c];
    float a = ((bf2f(u & 0xffffu) - m0) * r0 * w + bb) * bf2f(vv & 0xffffu);
    float d = ((bf2f(u >> 16) - m1) * r1 * w + bb) * bf2f(vv >> 16);
    *(u32*)(ab + (size_t)c * HW) = (u32)f2bf(a) | ((u32)f2bf(d) << 16);
  }
}

// ---- B-tile gather helper: u32 = 2 adjacent pixels, 8 channels -> 2 uint4 --
__device__ __forceinline__ void gatherB(const u16* __restrict__ src,
                                        uint4& e, uint4& o)
{
  u32 w0 = *(const u32*)(src);
  u32 w1 = *(const u32*)(src + HW);
  u32 w2 = *(const u32*)(src + 2 * HW);
  u32 w3 = *(const u32*)(src + 3 * HW);
  u32 w4 = *(const u32*)(src + 4 * HW);
  u32 w5 = *(const u32*)(src + 5 * HW);
  u32 w6 = *(const u32*)(src + 6 * HW);
  u32 w7 = *(const u32*)(src + 7 * HW);
  e.x = (w0 & 0xffffu) | (w1 << 16);
  e.y = (w2 & 0xffffu) | (w3 << 16);
  e.z = (w4 & 0xffffu) | (w5 << 16);
  e.w = (w6 & 0xffffu) | (w7 << 16);
  o.x = (w0 >> 16) | (w1 & 0xffff0000u);
  o.y = (w2 >> 16) | (w3 & 0xffff0000u);
  o.z = (w4 >> 16) | (w5 & 0xffff0000u);
  o.w = (w6 >> 16) | (w7 & 0xffff0000u);
}

// ---------------- chunked conv1x1 GEMM (for K=256 / single M-tile cases) ----
// EPI: 2 res[o,p] + acc*scale[o].  AUXF32: residual fp32. OUTF32: Y fp32.
template <int AUXF32, int OUTF32>
__global__ __launch_bounds__(256, 2)
void gemm_k(const float* __restrict__ Wt, const u16* __restrict__ X,
            void* __restrict__ Yv, const void* __restrict__ aux,
            const float* __restrict__ scale, int M, int K, int xbatch)
{
  __shared__ __align__(16) u16 As[4][128][8];   // [kchunk][o][8]
  __shared__ __align__(16) u16 Bs[4][128][8];   // [kchunk][pixel][8]
  int mtiles = M >> 7;
  int mt = blockIdx.x % mtiles;
  int ntile = blockIdx.x / mtiles;
  int n0g = ntile << 7;
  int b = n0g >> 16;
  int p0 = n0g & (HW - 1);
  int o0 = mt << 7;
  const u16* Xb = X + (size_t)b * xbatch * HW;
  int t = threadIdx.x;
  int lane = t & 63, wv = t >> 6;
  int rb = (wv & 1) << 6, cb = (wv >> 1) << 6;
  int qd = lane >> 4, ln = lane & 15;
  f32x4 acc[4][4] = {};
  for (int c0 = 0; c0 < K; c0 += 32) {
    // stage A (fp32 weights -> bf16): 128 rows x 32 cols
#pragma unroll
    for (int it = 0; it < 2; ++it) {
      int tt = t + it * 256;
      int row = tt >> 2, ch = tt & 3;
      const float* wsrc = Wt + (size_t)(o0 + row) * K + c0 + ch * 8;
      uint4 pk;
      pk.x = (u32)f2bf(wsrc[0]) | ((u32)f2bf(wsrc[1]) << 16);
      pk.y = (u32)f2bf(wsrc[2]) | ((u32)f2bf(wsrc[3]) << 16);
      pk.z = (u32)f2bf(wsrc[4]) | ((u32)f2bf(wsrc[5]) << 16);
      pk.w = (u32)f2bf(wsrc[6]) | ((u32)f2bf(wsrc[7]) << 16);
      *(uint4*)&As[ch][row][0] = pk;
    }
    // stage B: u32 pixel-pair gather, 64 pairs x 4 kchunks = 256 slots
    {
      int pp = (t & 63) << 1;
      int kc = t >> 6;
      const u16* src = Xb + (size_t)(c0 + kc * 8) * HW + p0 + pp;
      uint4 e, o;
      gatherB(src, e, o);
      *(uint4*)&Bs[kc][pp][0] = e;
      *(uint4*)&Bs[kc][pp + 1][0] = o;
    }
    __syncthreads();
    bf16x8 af[4], bfv[4];
#pragma unroll
    for (int i = 0; i < 4; ++i) {
      af[i] = *(const bf16x8*)&As[qd][rb + i * 16 + ln][0];
      bfv[i] = *(const bf16x8*)&Bs[qd][cb + i * 16 + ln][0];
    }
#pragma unroll
    for (int i = 0; i < 4; ++i)
#pragma unroll
      for (int j = 0; j < 4; ++j)
        acc[i][j] = __builtin_amdgcn_mfma_f32_16x16x32_bf16(af[i], bfv[j],
                                                            acc[i][j], 0, 0, 0);
    __syncthreads();
  }
  size_t ybase = (size_t)b * M * HW;
#pragma unroll
  for (int i = 0; i < 4; ++i) {
    int obase = o0 + rb + i * 16 + qd * 4;
#pragma unroll
    for (int j = 0; j < 4; ++j) {
      int p = p0 + cb + j * 16 + ln;
#pragma unroll
      for (int rr = 0; rr < 4; ++rr) {
        int o = obase + rr;
        size_t idx = ybase + (size_t)o * HW + p;
        float v = acc[i][j][rr];
        float r = AUXF32 ? ((const float*)aux)[idx]
                         : bf2f((u32)((const u16*)aux)[idx]);
        v = r + v * scale[o];
        if (OUTF32) ((float*)Yv)[idx] = v;
        else        ((u16*)Yv)[idx] = f2bf(v);
      }
    }
  }
}

// ---------------- folded conv1x1 GEMM, K=128: B-tile staged ONCE, ------------
// loop over MT M-tiles reusing it. EPI: 0 plain, 1 +bias[o]. Y bf16.
template <int EPI>
__global__ __launch_bounds__(256, 2)
void gemmf_k(const float* __restrict__ Wt, const u16* __restrict__ X,
             u16* __restrict__ Y, const float* __restrict__ bias,
             int MT, int xbatch)
{
  __shared__ __align__(16) u16 Bs[16][128][8];   // full-K B tile, 32 KB
  __shared__ __align__(16) u16 As[16][128][8];   // full-K A tile, 32 KB
  int n0g = blockIdx.x << 7;
  int b = n0g >> 16;
  int p0 = n0g & (HW - 1);
  const u16* Xb = X + (size_t)b * xbatch * HW;
  int t = threadIdx.x;
  int lane = t & 63, wv = t >> 6;
  int rb = (wv & 1) << 6, cb = (wv >> 1) << 6;
  int qd = lane >> 4, ln = lane & 15;
  // stage B once: 64 pixel-pairs x 16 kchunks = 1024 slots, 4 iters
#pragma unroll
  for (int it = 0; it < 4; ++it) {
    int tt = t + it * 256;
    int pp = (tt & 63) << 1;
    int kc = tt >> 6;
    const u16* src = Xb + (size_t)(kc * 8) * HW + p0 + pp;
    uint4 e, o;
    gatherB(src, e, o);
    *(uint4*)&Bs[kc][pp][0] = e;
    *(uint4*)&Bs[kc][pp + 1][0] = o;
  }
  int M = MT << 7;
  size_t ybase = (size_t)b * M * HW;
  for (int mt = 0; mt < MT; ++mt) {
    int o0 = mt << 7;
    __syncthreads();   // prior tile's MFMA reads done (mt=0: B writes done)
    // stage A tile, full K: 128 rows x 16 kchunks = 2048 slots, 8 iters
#pragma unroll
    for (int it = 0; it < 8; ++it) {
      int tt = t + it * 256;
      int row = tt & 127, kc = tt >> 7;
      const float* wsrc = Wt + (size_t)(o0 + row) * 128 + kc * 8;
      float4 w0 = *(const float4*)wsrc;
      float4 w1 = *(const float4*)(wsrc + 4);
      uint4 pk;
      pk.x = (u32)f2bf(w0.x) | ((u32)f2bf(w0.y) << 16);
      pk.y = (u32)f2bf(w0.z) | ((u32)f2bf(w0.w) << 16);
      pk.z = (u32)f2bf(w1.x) | ((u32)f2bf(w1.y) << 16);
      pk.w = (u32)f2bf(w1.z) | ((u32)f2bf(w1.w) << 16);
      *(uint4*)&As[kc][row][0] = pk;
    }
    __syncthreads();
    f32x4 acc[4][4] = {};
#pragma unroll
    for (int s = 0; s < 4; ++s) {
      bf16x8 af[4], bfv[4];
#pragma unroll
      for (int i = 0; i < 4; ++i) {
        af[i] = *(const bf16x8*)&As[s * 4 + qd][rb + i * 16 + ln][0];
        bfv[i] = *(const bf16x8*)&Bs[s * 4 + qd][cb + i * 16 + ln][0];
      }
#pragma unroll
      for (int i = 0; i < 4; ++i)
#pragma unroll
        for (int j = 0; j < 4; ++j)
          acc[i][j] = __builtin_amdgcn_mfma_f32_16x16x32_bf16(af[i], bfv[j],
                                                              acc[i][j], 0, 0, 0);
    }
#pragma unroll
    for (int i = 0; i < 4; ++i) {
      int obase = o0 + rb + i * 16 + qd * 4;
#pragma unroll
      for (int j = 0; j < 4; ++j) {
        int p = p0 + cb + j * 16 + ln;
#pragma unroll
        for (int rr = 0; rr < 4; ++rr) {
          int o = obase + rr;
          float v = acc[i][j][rr];
          if (EPI == 1) v += bias[o];
          Y[ybase + (size_t)o * HW + p] = f2bf(v);
        }
      }
    }
  }
}

// ---------------- depthwise 3x3, SAME zero pad, IN-PLACE (bf16 data) --------
__device__ __forceinline__ void ldsrow(const u16* __restrict__ img, int h,
                                       int w0, float* r) {
  if ((unsigned)h > 255u) {
#pragma unroll
    for (int i = 0; i < 10; ++i) r[i] = 0.f;
    return;
  }
  const u16* rp = img + (h << 8) + w0;
  float c[8];
  unpack8(*(const uint4*)rp, c);
#pragma unroll
  for (int i = 0; i < 8; ++i) r[i + 1] = c[i];
  r[0] = (w0 > 0) ? bf2f((u32)rp[-1]) : 0.f;
  r[9] = (w0 < 248) ? bf2f((u32)rp[8]) : 0.f;
}

__global__ __launch_bounds__(1024)
void dwip_k(u16* __restrict__ buf, const float* __restrict__ wt, int C)
{
  __shared__ __align__(16) u16 img[65536];   // 128 KB: full channel
  int bc = blockIdx.x;                       // b*C + c
  int c = bc % C;
  size_t base = (size_t)bc << 16;
  int t = threadIdx.x;
  uint4* simg = (uint4*)img;
  const uint4* gsrc = (const uint4*)(buf + base);
#pragma unroll
  for (int it = 0; it < 8; ++it)
    simg[it * 1024 + t] = gsrc[it * 1024 + t];
  float wg[9];
#pragma unroll
  for (int i = 0; i < 9; ++i) wg[i] = wt[c * 9 + i];
  __syncthreads();
  uint4* gdst = (uint4*)(buf + base);
#pragma unroll
  for (int it = 0; it < 8; ++it) {
    int f = it * 1024 + t;
    int h = f >> 5;
    int w0 = (f & 31) << 3;
    float r0[10], r1[10], r2[10];
    ldsrow(img, h - 1, w0, r0);
    ldsrow(img, h,     w0, r1);
    ldsrow(img, h + 1, w0, r2);
    float o[8];
#pragma unroll
    for (int j = 0; j < 8; ++j) {
      float s = 0.f;
#pragma unroll
      for (int dx = 0; dx < 3; ++dx)
        s += r0[j + dx] * wg[dx] + r1[j + dx] * wg[3 + dx] +
             r2[j + dx] * wg[6 + dx];
      o[j] = s;
    }
    uint4 pk;
    pk.x = (u32)f2bf(o[0]) | ((u32)f2bf(o[1]) << 16);
    pk.y = (u32)f2bf(o[2]) | ((u32)f2bf(o[3]) << 16);
    pk.z = (u32)f2bf(o[4]) | ((u32)f2bf(o[5]) << 16);
    pk.w = (u32)f2bf(o[6]) | ((u32)f2bf(o[7]) << 16);
    gdst[f] = pk;   // global write; LDS still holds pristine input
  }
}

// ---------------- patch-FFT attention = 8x8 circular conv per patch/channel -
// v2: no LDS. lane <-> one patch; q unpacked in 64 regs, k PACKED in 32 regs,
// output row streamed (acc 8 regs). In-place over q-slot (q is register-
// resident before first store; patches are lane-private).
__global__ __launch_bounds__(256, 3)
void attn_k(u16* __restrict__ qkv)
{
  int wv = threadIdx.x >> 6, lane = threadIdx.x & 63;
  int task = blockIdx.x * 4 + wv;       // 8192 tasks: b(2) x c(256) x strip(16)
  int b = task >> 12;
  int c = (task >> 4) & 255;
  int strip = task & 15;
  int pr = lane >> 5, pw = lane & 31;
  int row = (strip << 4) + (pr << 3);   // patch top row
  size_t qbase = ((size_t)(b * 768 + c) << 16) + ((size_t)row << 8) + pw * 8;
  size_t kbase = qbase + ((size_t)256 << 16);
  float qv[8][8];
  uint4 kp[8];
#pragma unroll
  for (int i = 0; i < 8; ++i) {
    unpack8(*(const uint4*)(qkv + qbase + (i << 8)), qv[i]);
    kp[i] = *(const uint4*)(qkv + kbase + (i << 8));
  }
#pragma unroll
  for (int m = 0; m < 8; ++m) {
    float a[8] = {};
#pragma unroll
    for (int i = 0; i < 8; ++i) {
      float kr[8];
      unpack8(kp[(m - i) & 7], kr);
#pragma unroll
      for (int n = 0; n < 8; ++n)
#pragma unroll
        for (int j = 0; j < 8; ++j)
          a[n] += qv[i][j] * kr[(n - j) & 7];
    }
    uint4 pk;
    pk.x = (u32)f2bf(a[0]) | ((u32)f2bf(a[1]) << 16);
    pk.y = (u32)f2bf(a[2]) | ((u32)f2bf(a[3]) << 16);
    pk.z = (u32)f2bf(a[4]) | ((u32)f2bf(a[5]) << 16);
    pk.w = (u32)f2bf(a[6]) | ((u32)f2bf(a[7]) << 16);
    *(uint4*)(qkv + qbase + (m << 8)) = pk;
  }
}

// ---------------- h1*h2 elementwise (FFN gate, bf16) ------------------------
__global__ __launch_bounds__(256)
void prod_k(const u16* __restrict__ g, u16* __restrict__ o)
{
  size_t i8 = ((size_t)blockIdx.x * 256 + threadIdx.x) * 8;
  int b = (int)(i8 >> 23);                 // 128*65536 = 2^23 per batch
  size_t rem = i8 & (((size_t)1 << 23) - 1);
  const u16* g1 = g + (((size_t)b * 256) << 16) + rem;
  const u16* g2 = g1 + ((size_t)128 << 16);
  uint4 ua = *(const uint4*)g1;
  uint4 ub = *(const uint4*)g2;
  uint4 pk;
  pk.x = (u32)f2bf(bf2f(ua.x & 0xffffu) * bf2f(ub.x & 0xffffu)) |
         ((u32)f2bf(bf2f(ua.x >> 16) * bf2f(ub.x >> 16)) << 16);
  pk.y = (u32)f2bf(bf2f(ua.y & 0xffffu) * bf2f(ub.y & 0xffffu)) |
         ((u32)f2bf(bf2f(ua.y >> 16) * bf2f(ub.y >> 16)) << 16);
  pk.z = (u32)f2bf(bf2f(ua.z & 0xffffu) * bf2f(ub.z & 0xffffu)) |
         ((u32)f2bf(bf2f(ua.z >> 16) * bf2f(ub.z >> 16)) << 16);
  pk.w = (u32)f2bf(bf2f(ua.w & 0xffffu) * bf2f(ub.w & 0xffffu)) |
         ((u32)f2bf(bf2f(ua.w >> 16) * bf2f(ub.w >> 16)) << 16);
  *(uint4*)(o + (((size_t)b * 128) << 16) + rem) = pk;
}

extern "C" void kernel_launch(void* const* d_in, const int* in_sizes, int n_in,
                              void* d_out, int out_size, void* d_ws, size_t ws_size,
                              hipStream_t stream)
{
  (void)in_sizes; (void)n_in; (void)out_size; (void)ws_size;
  const float* x    = (const float*)d_in[0];
  const float* n1w  = (const float*)d_in[1];
  const float* n1b  = (const float*)d_in[2];
  const float* wh1  = (const float*)d_in[3];
  const float* wdw1 = (const float*)d_in[4];
  const float* n2w  = (const float*)d_in[5];
  const float* n2b  = (const float*)d_in[6];
  const float* wp1  = (const float*)d_in[7];
  const float* n3w  = (const float*)d_in[8];
  const float* n3b  = (const float*)d_in[9];
  const float* wh2  = (const float*)d_in[10];
  const float* bh2  = (const float*)d_in[11];
  const float* wdw2 = (const float*)d_in[12];
  const float* wp2  = (const float*)d_in[13];
  const float* sc1  = (const float*)d_in[14];
  const float* sc2  = (const float*)d_in[15];
  float* out = (float*)d_out;
  u16* ws = (u16*)d_ws;

  // workspace (u16 elems), peak ~235 MB:
  //   A = ws          : 100,663,296 elems (2,768,HW)  hidden -> qkv -> attn/va
  //                     later: h3 [0,16.7M) | h4/gg [16.7M,50.3M) | pr [0,16.7M)
  //   B = ws + 100.7M :  16,777,216 elems (2,128,HW)  hln -> xmid (bf16)
  u16* A = ws;
  u16* B = ws + 100663296;
  u16* h3 = A;
  u16* h4 = A + 16777216;
  u16* pr = A;

  ln_k<1><<<256, 256, 0, stream>>>(x, n1w, n1b, B, 128);                     // hln
  gemmf_k<0><<<1024, 256, 0, stream>>>(wh1, B, A, nullptr, 6, 128);          // hidden
  dwip_k<<<1536, 1024, 0, stream>>>(A, wdw1, 768);                           // qkv
  attn_k<<<2048, 256, 0, stream>>>(A);                                       // attn -> q-slot
  ln2v_k<<<256, 256, 0, stream>>>(A, n2w, n2b);                              // va -> q-slot
  gemm_k<1,0><<<1024, 256, 0, stream>>>(wp1, A, B, x, sc1, 128, 256, 768);   // xmid -> B
  ln_k<0><<<256, 256, 0, stream>>>(B, n3w, n3b, h3, 128);
  gemmf_k<1><<<1024, 256, 0, stream>>>(wh2, h3, h4, bh2, 2, 128);            // h4
  dwip_k<<<512, 1024, 0, stream>>>(h4, wdw2, 256);                           // gg
  prod_k<<<8192, 256, 0, stream>>>(h4, pr);
  gemm_k<0,1><<<1024, 256, 0, stream>>>(wp2, pr, out, B, sc2, 128, 128, 128);
}

// Round 5
// 757.794 us; speedup vs baseline: 1.7631x; 1.7631x over previous
//
#include <hip/hip_runtime.h>

typedef unsigned short u16;
typedef unsigned int u32;
typedef __attribute__((ext_vector_type(8))) short bf16x8;
typedef __attribute__((ext_vector_type(4))) float f32x4;

#define HW 65536

__device__ __forceinline__ float bf2f(u32 v) { return __uint_as_float(v << 16); }
__device__ __forceinline__ u16 f2bf(float f) {
  u32 u = __float_as_uint(f);
  u += 0x7fffu + ((u >> 16) & 1u);   // RNE; inputs are finite
  return (u16)(u >> 16);
}

__device__ __forceinline__ void unpack8(uint4 u, float r[8]) {
  r[0] = bf2f(u.x & 0xffffu); r[1] = bf2f(u.x >> 16);
  r[2] = bf2f(u.y & 0xffffu); r[3] = bf2f(u.y >> 16);
  r[4] = bf2f(u.z & 0xffffu); r[5] = bf2f(u.z >> 16);
  r[6] = bf2f(u.w & 0xffffu); r[7] = bf2f(u.w >> 16);
}

// ---------------- LayerNorm over channel dim (thread = 2 adjacent pixels) ----
template <int INF32>
__global__ __launch_bounds__(256)
void ln_k(const void* __restrict__ xv, const float* __restrict__ gw,
          const float* __restrict__ gb, u16* __restrict__ y, int C)
{
  int pi = blockIdx.x * 256 + threadIdx.x;
  int p2 = pi << 1;
  int b = p2 >> 16;
  int p = p2 & (HW - 1);
  const float* xf = (const float*)xv + (size_t)b * C * HW + p;
  const u16* xh = (const u16*)xv + (size_t)b * C * HW + p;
  u16* yb = y + (size_t)b * C * HW + p;
  float s0 = 0, s1 = 0, q0 = 0, q1 = 0;
  for (int c = 0; c < C; ++c) {
    float a, d;
    if (INF32) {
      float2 u = *(const float2*)(xf + (size_t)c * HW);
      a = u.x; d = u.y;
    } else {
      u32 u = *(const u32*)(xh + (size_t)c * HW);
      a = bf2f(u & 0xffffu); d = bf2f(u >> 16);
    }
    s0 += a; q0 += a * a; s1 += d; q1 += d * d;
  }
  float inv = 1.0f / (float)C;
  float m0 = s0 * inv, m1 = s1 * inv;
  float r0 = rsqrtf(fmaxf(q0 * inv - m0 * m0, 0.f) + 1e-6f);
  float r1 = rsqrtf(fmaxf(q1 * inv - m1 * m1, 0.f) + 1e-6f);
  for (int c = 0; c < C; ++c) {
    float a, d;
    if (INF32) {
      float2 u = *(const float2*)(xf + (size_t)c * HW);
      a = u.x; d = u.y;
    } else {
      u32 u = *(const u32*)(xh + (size_t)c * HW);
      a = bf2f(u & 0xffffu); d = bf2f(u >> 16);
    }
    float w = gw[c], bb = gb[c];
    a = (a - m0) * r0 * w + bb;
    d = (d - m1) * r1 * w + bb;
    *(u32*)(yb + (size_t)c * HW) = (u32)f2bf(a) | ((u32)f2bf(d) << 16);
  }
}

// ---------------- LN2 over 256 channels fused with v-multiply ---------------
__global__ __launch_bounds__(256)
void ln2v_k(u16* __restrict__ qkv, const float* __restrict__ gw,
            const float* __restrict__ gb)
{
  int pi = blockIdx.x * 256 + threadIdx.x;
  int p2 = pi << 1;
  int b = p2 >> 16;
  int p = p2 & (HW - 1);
  u16* ab = qkv + ((size_t)(b * 768) << 16) + p;               // attn (q-slot)
  const u16* vb = qkv + ((size_t)(b * 768 + 512) << 16) + p;   // v
  float s0 = 0, s1 = 0, q0 = 0, q1 = 0;
  for (int c = 0; c < 256; ++c) {
    u32 u = *(const u32*)(ab + (size_t)c * HW);
    float a = bf2f(u & 0xffffu), d = bf2f(u >> 16);
    s0 += a; q0 += a * a; s1 += d; q1 += d * d;
  }
  const float inv = 1.0f / 256.0f;
  float m0 = s0 * inv, m1 = s1 * inv;
  float r0 = rsqrtf(fmaxf(q0 * inv - m0 * m0, 0.f) + 1e-6f);
  float r1 = rsqrtf(fmaxf(q1 * inv - m1 * m1, 0.f) + 1e-6f);
  for (int c = 0; c < 256; ++c) {
    u32 u = *(const u32*)(ab + (size_t)c * HW);
    u32 vv = *(const u32*)(vb + (size_t)c * HW);
    float w = gw[c], bb = gb[c];
    float a = ((bf2f(u & 0xffffu) - m0) * r0 * w + bb) * bf2f(vv & 0xffffu);
    float d = ((bf2f(u >> 16) - m1) * r1 * w + bb) * bf2f(vv >> 16);
    *(u32*)(ab + (size_t)c * HW) = (u32)f2bf(a) | ((u32)f2bf(d) << 16);
  }
}

// ---- B-tile gather helper: u32 = 2 adjacent pixels, 8 channels -> 2 uint4 --
__device__ __forceinline__ void gatherB(const u16* __restrict__ src,
                                        uint4& e, uint4& o)
{
  u32 w0 = *(const u32*)(src);
  u32 w1 = *(const u32*)(src + HW);
  u32 w2 = *(const u32*)(src + 2 * HW);
  u32 w3 = *(const u32*)(src + 3 * HW);
  u32 w4 = *(const u32*)(src + 4 * HW);
  u32 w5 = *(const u32*)(src + 5 * HW);
  u32 w6 = *(const u32*)(src + 6 * HW);
  u32 w7 = *(const u32*)(src + 7 * HW);
  e.x = (w0 & 0xffffu) | (w1 << 16);
  e.y = (w2 & 0xffffu) | (w3 << 16);
  e.z = (w4 & 0xffffu) | (w5 << 16);
  e.w = (w6 & 0xffffu) | (w7 << 16);
  o.x = (w0 >> 16) | (w1 & 0xffff0000u);
  o.y = (w2 >> 16) | (w3 & 0xffff0000u);
  o.z = (w4 >> 16) | (w5 & 0xffff0000u);
  o.w = (w6 >> 16) | (w7 & 0xffff0000u);
}

// ---------------- chunked conv1x1 GEMM (K=256 / single-M cases) -------------
// Epilogue: res[o,p] + acc*scale[o]. AUXF32: residual fp32. OUTF32: Y fp32.
template <int AUXF32, int OUTF32>
__global__ __launch_bounds__(256, 2)
void gemm_k(const float* __restrict__ Wt, const u16* __restrict__ X,
            void* __restrict__ Yv, const void* __restrict__ aux,
            const float* __restrict__ scale, int M, int K, int xbatch)
{
  __shared__ __align__(16) u16 As[4][128][8];   // [kchunk][o][8]
  __shared__ __align__(16) u16 Bs[4][128][8];   // [kchunk][pixel][8]
  int mtiles = M >> 7;
  int mt = blockIdx.x % mtiles;
  int ntile = blockIdx.x / mtiles;
  int n0g = ntile << 7;
  int b = n0g >> 16;
  int p0 = n0g & (HW - 1);
  int o0 = mt << 7;
  const u16* Xb = X + (size_t)b * xbatch * HW;
  int t = threadIdx.x;
  int lane = t & 63, wv = t >> 6;
  int rb = (wv & 1) << 6, cb = (wv >> 1) << 6;
  int qd = lane >> 4, ln = lane & 15;
  f32x4 acc[4][4] = {};
  for (int c0 = 0; c0 < K; c0 += 32) {
#pragma unroll
    for (int it = 0; it < 2; ++it) {
      int tt = t + it * 256;
      int row = tt >> 2, ch = tt & 3;
      const float* wsrc = Wt + (size_t)(o0 + row) * K + c0 + ch * 8;
      uint4 pk;
      pk.x = (u32)f2bf(wsrc[0]) | ((u32)f2bf(wsrc[1]) << 16);
      pk.y = (u32)f2bf(wsrc[2]) | ((u32)f2bf(wsrc[3]) << 16);
      pk.z = (u32)f2bf(wsrc[4]) | ((u32)f2bf(wsrc[5]) << 16);
      pk.w = (u32)f2bf(wsrc[6]) | ((u32)f2bf(wsrc[7]) << 16);
      *(uint4*)&As[ch][row][0] = pk;
    }
    {
      int pp = (t & 63) << 1;
      int kc = t >> 6;
      const u16* src = Xb + (size_t)(c0 + kc * 8) * HW + p0 + pp;
      uint4 e, o;
      gatherB(src, e, o);
      *(uint4*)&Bs[kc][pp][0] = e;
      *(uint4*)&Bs[kc][pp + 1][0] = o;
    }
    __syncthreads();
    bf16x8 af[4], bfv[4];
#pragma unroll
    for (int i = 0; i < 4; ++i) {
      af[i] = *(const bf16x8*)&As[qd][rb + i * 16 + ln][0];
      bfv[i] = *(const bf16x8*)&Bs[qd][cb + i * 16 + ln][0];
    }
#pragma unroll
    for (int i = 0; i < 4; ++i)
#pragma unroll
      for (int j = 0; j < 4; ++j)
        acc[i][j] = __builtin_amdgcn_mfma_f32_16x16x32_bf16(af[i], bfv[j],
                                                            acc[i][j], 0, 0, 0);
    __syncthreads();
  }
  size_t ybase = (size_t)b * M * HW;
#pragma unroll
  for (int i = 0; i < 4; ++i) {
    int obase = o0 + rb + i * 16 + qd * 4;
#pragma unroll
    for (int j = 0; j < 4; ++j) {
      int p = p0 + cb + j * 16 + ln;
#pragma unroll
      for (int rr = 0; rr < 4; ++rr) {
        int o = obase + rr;
        size_t idx = ybase + (size_t)o * HW + p;
        float v = acc[i][j][rr];
        float r = AUXF32 ? ((const float*)aux)[idx]
                         : bf2f((u32)((const u16*)aux)[idx]);
        v = r + v * scale[o];
        if (OUTF32) ((float*)Yv)[idx] = v;
        else        ((u16*)Yv)[idx] = f2bf(v);
      }
    }
  }
}

// ---------------- folded conv1x1 GEMM, K=128: B-tile staged ONCE ------------
template <int EPI>
__global__ __launch_bounds__(256, 2)
void gemmf_k(const float* __restrict__ Wt, const u16* __restrict__ X,
             u16* __restrict__ Y, const float* __restrict__ bias,
             int MT, int xbatch)
{
  __shared__ __align__(16) u16 Bs[16][128][8];   // full-K B tile, 32 KB
  __shared__ __align__(16) u16 As[16][128][8];   // full-K A tile, 32 KB
  int n0g = blockIdx.x << 7;
  int b = n0g >> 16;
  int p0 = n0g & (HW - 1);
  const u16* Xb = X + (size_t)b * xbatch * HW;
  int t = threadIdx.x;
  int lane = t & 63, wv = t >> 6;
  int rb = (wv & 1) << 6, cb = (wv >> 1) << 6;
  int qd = lane >> 4, ln = lane & 15;
#pragma unroll
  for (int it = 0; it < 4; ++it) {
    int tt = t + it * 256;
    int pp = (tt & 63) << 1;
    int kc = tt >> 6;
    const u16* src = Xb + (size_t)(kc * 8) * HW + p0 + pp;
    uint4 e, o;
    gatherB(src, e, o);
    *(uint4*)&Bs[kc][pp][0] = e;
    *(uint4*)&Bs[kc][pp + 1][0] = o;
  }
  int M = MT << 7;
  size_t ybase = (size_t)b * M * HW;
  for (int mt = 0; mt < MT; ++mt) {
    int o0 = mt << 7;
    __syncthreads();   // prior tile's MFMA reads done (mt=0: B writes done)
#pragma unroll
    for (int it = 0; it < 8; ++it) {
      int tt = t + it * 256;
      int row = tt & 127, kc = tt >> 7;
      const float* wsrc = Wt + (size_t)(o0 + row) * 128 + kc * 8;
      float4 w0 = *(const float4*)wsrc;
      float4 w1 = *(const float4*)(wsrc + 4);
      uint4 pk;
      pk.x = (u32)f2bf(w0.x) | ((u32)f2bf(w0.y) << 16);
      pk.y = (u32)f2bf(w0.z) | ((u32)f2bf(w0.w) << 16);
      pk.z = (u32)f2bf(w1.x) | ((u32)f2bf(w1.y) << 16);
      pk.w = (u32)f2bf(w1.z) | ((u32)f2bf(w1.w) << 16);
      *(uint4*)&As[kc][row][0] = pk;
    }
    __syncthreads();
    f32x4 acc[4][4] = {};
#pragma unroll
    for (int s = 0; s < 4; ++s) {
      bf16x8 af[4], bfv[4];
#pragma unroll
      for (int i = 0; i < 4; ++i) {
        af[i] = *(const bf16x8*)&As[s * 4 + qd][rb + i * 16 + ln][0];
        bfv[i] = *(const bf16x8*)&Bs[s * 4 + qd][cb + i * 16 + ln][0];
      }
#pragma unroll
      for (int i = 0; i < 4; ++i)
#pragma unroll
        for (int j = 0; j < 4; ++j)
          acc[i][j] = __builtin_amdgcn_mfma_f32_16x16x32_bf16(af[i], bfv[j],
                                                              acc[i][j], 0, 0, 0);
    }
#pragma unroll
    for (int i = 0; i < 4; ++i) {
      int obase = o0 + rb + i * 16 + qd * 4;
#pragma unroll
      for (int j = 0; j < 4; ++j) {
        int p = p0 + cb + j * 16 + ln;
#pragma unroll
        for (int rr = 0; rr < 4; ++rr) {
          int o = obase + rr;
          float v = acc[i][j][rr];
          if (EPI == 1) v += bias[o];
          Y[ybase + (size_t)o * HW + p] = f2bf(v);
        }
      }
    }
  }
}

// ---------------- depthwise 3x3, SAME zero pad, IN-PLACE (bf16 data) --------
__device__ __forceinline__ void ldsrow(const u16* __restrict__ img, int h,
                                       int w0, float* r) {
  if ((unsigned)h > 255u) {
#pragma unroll
    for (int i = 0; i < 10; ++i) r[i] = 0.f;
    return;
  }
  const u16* rp = img + (h << 8) + w0;
  float c[8];
  unpack8(*(const uint4*)rp, c);
#pragma unroll
  for (int i = 0; i < 8; ++i) r[i + 1] = c[i];
  r[0] = (w0 > 0) ? bf2f((u32)rp[-1]) : 0.f;
  r[9] = (w0 < 248) ? bf2f((u32)rp[8]) : 0.f;
}

__global__ __launch_bounds__(1024)
void dwip_k(u16* __restrict__ buf, const float* __restrict__ wt, int C)
{
  __shared__ __align__(16) u16 img[65536];   // 128 KB: full channel
  int bc = blockIdx.x;                       // b*C + c
  int c = bc % C;
  size_t base = (size_t)bc << 16;
  int t = threadIdx.x;
  uint4* simg = (uint4*)img;
  const uint4* gsrc = (const uint4*)(buf + base);
#pragma unroll
  for (int it = 0; it < 8; ++it)
    simg[it * 1024 + t] = gsrc[it * 1024 + t];
  float wg[9];
#pragma unroll
  for (int i = 0; i < 9; ++i) wg[i] = wt[c * 9 + i];
  __syncthreads();
  uint4* gdst = (uint4*)(buf + base);
#pragma unroll
  for (int it = 0; it < 8; ++it) {
    int f = it * 1024 + t;
    int h = f >> 5;
    int w0 = (f & 31) << 3;
    float r0[10], r1[10], r2[10];
    ldsrow(img, h - 1, w0, r0);
    ldsrow(img, h,     w0, r1);
    ldsrow(img, h + 1, w0, r2);
    float o[8];
#pragma unroll
    for (int j = 0; j < 8; ++j) {
      float s = 0.f;
#pragma unroll
      for (int dx = 0; dx < 3; ++dx)
        s += r0[j + dx] * wg[dx] + r1[j + dx] * wg[3 + dx] +
             r2[j + dx] * wg[6 + dx];
      o[j] = s;
    }
    uint4 pk;
    pk.x = (u32)f2bf(o[0]) | ((u32)f2bf(o[1]) << 16);
    pk.y = (u32)f2bf(o[2]) | ((u32)f2bf(o[3]) << 16);
    pk.z = (u32)f2bf(o[4]) | ((u32)f2bf(o[5]) << 16);
    pk.w = (u32)f2bf(o[6]) | ((u32)f2bf(o[7]) << 16);
    gdst[f] = pk;   // global write; LDS still holds pristine input
  }
}

// ---------------- patch-FFT attention = 8x8 circular conv per patch/channel -
// v3: acc-resident, q-streaming. kv fully unpacked (64 regs) + acc (64 regs)
// + one q row (8 regs) => ~145 live, NO launch-bounds min => no spill
// (R4 lesson: (256,3) hint made the compiler cap at 84 VGPR and spill 2.3 GB
// of scratch traffic). In-place over q-slot: lane-private patches, each q row
// read before any store.
__global__ __launch_bounds__(256)
void attn_k(u16* __restrict__ qkv)
{
  int wv = threadIdx.x >> 6, lane = threadIdx.x & 63;
  int task = blockIdx.x * 4 + wv;       // 8192 tasks: b(2) x c(256) x strip(16)
  int b = task >> 12;
  int c = (task >> 4) & 255;
  int strip = task & 15;
  int pr = lane >> 5, pw = lane & 31;
  int row = (strip << 4) + (pr << 3);   // patch top row
  size_t qbase = ((size_t)(b * 768 + c) << 16) + ((size_t)row << 8) + pw * 8;
  size_t kbase = qbase + ((size_t)256 << 16);
  float kv[8][8];
#pragma unroll
  for (int i = 0; i < 8; ++i)
    unpack8(*(const uint4*)(qkv + kbase + (i << 8)), kv[i]);
  float acc[8][8] = {};
#pragma unroll
  for (int i = 0; i < 8; ++i) {
    float qi[8];
    unpack8(*(const uint4*)(qkv + qbase + (i << 8)), qi);
#pragma unroll
    for (int m = 0; m < 8; ++m) {
      const int r = (m - i) & 7;
#pragma unroll
      for (int n = 0; n < 8; ++n)
#pragma unroll
        for (int j = 0; j < 8; ++j)
          acc[m][n] += qi[j] * kv[r][(n - j) & 7];
    }
  }
#pragma unroll
  for (int m = 0; m < 8; ++m) {
    uint4 pk;
    pk.x = (u32)f2bf(acc[m][0]) | ((u32)f2bf(acc[m][1]) << 16);
    pk.y = (u32)f2bf(acc[m][2]) | ((u32)f2bf(acc[m][3]) << 16);
    pk.z = (u32)f2bf(acc[m][4]) | ((u32)f2bf(acc[m][5]) << 16);
    pk.w = (u32)f2bf(acc[m][6]) | ((u32)f2bf(acc[m][7]) << 16);
    *(uint4*)(qkv + qbase + (m << 8)) = pk;
  }
}

// ---------------- h1*h2 elementwise (FFN gate, bf16) ------------------------
__global__ __launch_bounds__(256)
void prod_k(const u16* __restrict__ g, u16* __restrict__ o)
{
  size_t i8 = ((size_t)blockIdx.x * 256 + threadIdx.x) * 8;
  int b = (int)(i8 >> 23);                 // 128*65536 = 2^23 per batch
  size_t rem = i8 & (((size_t)1 << 23) - 1);
  const u16* g1 = g + (((size_t)b * 256) << 16) + rem;
  const u16* g2 = g1 + ((size_t)128 << 16);
  uint4 ua = *(const uint4*)g1;
  uint4 ub = *(const uint4*)g2;
  uint4 pk;
  pk.x = (u32)f2bf(bf2f(ua.x & 0xffffu) * bf2f(ub.x & 0xffffu)) |
         ((u32)f2bf(bf2f(ua.x >> 16) * bf2f(ub.x >> 16)) << 16);
  pk.y = (u32)f2bf(bf2f(ua.y & 0xffffu) * bf2f(ub.y & 0xffffu)) |
         ((u32)f2bf(bf2f(ua.y >> 16) * bf2f(ub.y >> 16)) << 16);
  pk.z = (u32)f2bf(bf2f(ua.z & 0xffffu) * bf2f(ub.z & 0xffffu)) |
         ((u32)f2bf(bf2f(ua.z >> 16) * bf2f(ub.z >> 16)) << 16);
  pk.w = (u32)f2bf(bf2f(ua.w & 0xffffu) * bf2f(ub.w & 0xffffu)) |
         ((u32)f2bf(bf2f(ua.w >> 16) * bf2f(ub.w >> 16)) << 16);
  *(uint4*)(o + (((size_t)b * 128) << 16) + rem) = pk;
}

extern "C" void kernel_launch(void* const* d_in, const int* in_sizes, int n_in,
                              void* d_out, int out_size, void* d_ws, size_t ws_size,
                              hipStream_t stream)
{
  (void)in_sizes; (void)n_in; (void)out_size; (void)ws_size;
  const float* x    = (const float*)d_in[0];
  const float* n1w  = (const float*)d_in[1];
  const float* n1b  = (const float*)d_in[2];
  const float* wh1  = (const float*)d_in[3];
  const float* wdw1 = (const float*)d_in[4];
  const float* n2w  = (const float*)d_in[5];
  const float* n2b  = (const float*)d_in[6];
  const float* wp1  = (const float*)d_in[7];
  const float* n3w  = (const float*)d_in[8];
  const float* n3b  = (const float*)d_in[9];
  const float* wh2  = (const float*)d_in[10];
  const float* bh2  = (const float*)d_in[11];
  const float* wdw2 = (const float*)d_in[12];
  const float* wp2  = (const float*)d_in[13];
  const float* sc1  = (const float*)d_in[14];
  const float* sc2  = (const float*)d_in[15];
  float* out = (float*)d_out;
  u16* ws = (u16*)d_ws;

  // workspace (u16 elems), peak ~235 MB:
  //   A = ws          : (2,768,HW)  hidden -> qkv -> attn/va
  //                     later: h3 [0,16.7M) | h4/gg [16.7M,50.3M) | pr [0,16.7M)
  //   B = ws + 100.7M : (2,128,HW)  hln -> xmid (bf16)
  u16* A = ws;
  u16* B = ws + 100663296;
  u16* h3 = A;
  u16* h4 = A + 16777216;
  u16* pr = A;

  ln_k<1><<<256, 256, 0, stream>>>(x, n1w, n1b, B, 128);                     // hln
  gemmf_k<0><<<1024, 256, 0, stream>>>(wh1, B, A, nullptr, 6, 128);          // hidden
  dwip_k<<<1536, 1024, 0, stream>>>(A, wdw1, 768);                           // qkv
  attn_k<<<2048, 256, 0, stream>>>(A);                                       // attn -> q-slot
  ln2v_k<<<256, 256, 0, stream>>>(A, n2w, n2b);                              // va -> q-slot
  gemm_k<1,0><<<1024, 256, 0, stream>>>(wp1, A, B, x, sc1, 128, 256, 768);   // xmid -> B
  ln_k<0><<<256, 256, 0, stream>>>(B, n3w, n3b, h3, 128);
  gemmf_k<1><<<1024, 256, 0, stream>>>(wh2, h3, h4, bh2, 2, 128);            // h4
  dwip_k<<<512, 1024, 0, stream>>>(h4, wdw2, 256);                           // gg
  prod_k<<<8192, 256, 0, stream>>>(h4, pr);
  gemm_k<0,1><<<1024, 256, 0, stream>>>(wp2, pr, out, B, sc2, 128, 128, 128);
}

// Round 6
// 712.667 us; speedup vs baseline: 1.8748x; 1.0633x over previous
//
#include <hip/hip_runtime.h>

typedef unsigned short u16;
typedef unsigned int u32;
typedef __attribute__((ext_vector_type(8))) short bf16x8;
typedef __attribute__((ext_vector_type(4))) float f32x4;

#define HW 65536

__device__ __forceinline__ float bf2f(u32 v) { return __uint_as_float(v << 16); }
__device__ __forceinline__ u16 f2bf(float f) {
  u32 u = __float_as_uint(f);
  u += 0x7fffu + ((u >> 16) & 1u);   // RNE; inputs are finite
  return (u16)(u >> 16);
}

// packed bf16 dot2: d = a.l*b.l + a.h*b.h + d  (CDNA VOP3P v_dot2_f32_bf16)
__device__ __forceinline__ float dot2bf(u32 a, u32 b, float d) {
  asm("v_dot2_f32_bf16 %0, %1, %2, %0" : "+v"(d) : "v"(a), "v"(b));
  return d;
}

__device__ __forceinline__ void unpack8(uint4 u, float r[8]) {
  r[0] = bf2f(u.x & 0xffffu); r[1] = bf2f(u.x >> 16);
  r[2] = bf2f(u.y & 0xffffu); r[3] = bf2f(u.y >> 16);
  r[4] = bf2f(u.z & 0xffffu); r[5] = bf2f(u.z >> 16);
  r[6] = bf2f(u.w & 0xffffu); r[7] = bf2f(u.w >> 16);
}

// ---------------- LayerNorm over channel dim (thread = 2 adjacent pixels) ----
template <int INF32>
__global__ __launch_bounds__(256)
void ln_k(const void* __restrict__ xv, const float* __restrict__ gw,
          const float* __restrict__ gb, u16* __restrict__ y, int C)
{
  int pi = blockIdx.x * 256 + threadIdx.x;
  int p2 = pi << 1;
  int b = p2 >> 16;
  int p = p2 & (HW - 1);
  const float* xf = (const float*)xv + (size_t)b * C * HW + p;
  const u16* xh = (const u16*)xv + (size_t)b * C * HW + p;
  u16* yb = y + (size_t)b * C * HW + p;
  float s0 = 0, s1 = 0, q0 = 0, q1 = 0;
  for (int c = 0; c < C; ++c) {
    float a, d;
    if (INF32) {
      float2 u = *(const float2*)(xf + (size_t)c * HW);
      a = u.x; d = u.y;
    } else {
      u32 u = *(const u32*)(xh + (size_t)c * HW);
      a = bf2f(u & 0xffffu); d = bf2f(u >> 16);
    }
    s0 += a; q0 += a * a; s1 += d; q1 += d * d;
  }
  float inv = 1.0f / (float)C;
  float m0 = s0 * inv, m1 = s1 * inv;
  float r0 = rsqrtf(fmaxf(q0 * inv - m0 * m0, 0.f) + 1e-6f);
  float r1 = rsqrtf(fmaxf(q1 * inv - m1 * m1, 0.f) + 1e-6f);
  for (int c = 0; c < C; ++c) {
    float a, d;
    if (INF32) {
      float2 u = *(const float2*)(xf + (size_t)c * HW);
      a = u.x; d = u.y;
    } else {
      u32 u = *(const u32*)(xh + (size_t)c * HW);
      a = bf2f(u & 0xffffu); d = bf2f(u >> 16);
    }
    float w = gw[c], bb = gb[c];
    a = (a - m0) * r0 * w + bb;
    d = (d - m1) * r1 * w + bb;
    *(u32*)(yb + (size_t)c * HW) = (u32)f2bf(a) | ((u32)f2bf(d) << 16);
  }
}

// ---------------- LN2 over 256 channels fused with v-multiply ---------------
__global__ __launch_bounds__(256)
void ln2v_k(u16* __restrict__ qkv, const float* __restrict__ gw,
            const float* __restrict__ gb)
{
  int pi = blockIdx.x * 256 + threadIdx.x;
  int p2 = pi << 1;
  int b = p2 >> 16;
  int p = p2 & (HW - 1);
  u16* ab = qkv + ((size_t)(b * 768) << 16) + p;               // attn (q-slot)
  const u16* vb = qkv + ((size_t)(b * 768 + 512) << 16) + p;   // v
  float s0 = 0, s1 = 0, q0 = 0, q1 = 0;
  for (int c = 0; c < 256; ++c) {
    u32 u = *(const u32*)(ab + (size_t)c * HW);
    float a = bf2f(u & 0xffffu), d = bf2f(u >> 16);
    s0 += a; q0 += a * a; s1 += d; q1 += d * d;
  }
  const float inv = 1.0f / 256.0f;
  float m0 = s0 * inv, m1 = s1 * inv;
  float r0 = rsqrtf(fmaxf(q0 * inv - m0 * m0, 0.f) + 1e-6f);
  float r1 = rsqrtf(fmaxf(q1 * inv - m1 * m1, 0.f) + 1e-6f);
  for (int c = 0; c < 256; ++c) {
    u32 u = *(const u32*)(ab + (size_t)c * HW);
    u32 vv = *(const u32*)(vb + (size_t)c * HW);
    float w = gw[c], bb = gb[c];
    float a = ((bf2f(u & 0xffffu) - m0) * r0 * w + bb) * bf2f(vv & 0xffffu);
    float d = ((bf2f(u >> 16) - m1) * r1 * w + bb) * bf2f(vv >> 16);
    *(u32*)(ab + (size_t)c * HW) = (u32)f2bf(a) | ((u32)f2bf(d) << 16);
  }
}

// ---- B-tile gather helper: u32 = 2 adjacent pixels, 8 channels -> 2 uint4 --
__device__ __forceinline__ void gatherB(const u16* __restrict__ src,
                                        uint4& e, uint4& o)
{
  u32 w0 = *(const u32*)(src);
  u32 w1 = *(const u32*)(src + HW);
  u32 w2 = *(const u32*)(src + 2 * HW);
  u32 w3 = *(const u32*)(src + 3 * HW);
  u32 w4 = *(const u32*)(src + 4 * HW);
  u32 w5 = *(const u32*)(src + 5 * HW);
  u32 w6 = *(const u32*)(src + 6 * HW);
  u32 w7 = *(const u32*)(src + 7 * HW);
  e.x = (w0 & 0xffffu) | (w1 << 16);
  e.y = (w2 & 0xffffu) | (w3 << 16);
  e.z = (w4 & 0xffffu) | (w5 << 16);
  e.w = (w6 & 0xffffu) | (w7 << 16);
  o.x = (w0 >> 16) | (w1 & 0xffff0000u);
  o.y = (w2 >> 16) | (w3 & 0xffff0000u);
  o.z = (w4 >> 16) | (w5 & 0xffff0000u);
  o.w = (w6 >> 16) | (w7 & 0xffff0000u);
}

// ---------------- chunked conv1x1 GEMM (K=256 / single-M cases) -------------
// Epilogue: res[o,p] + acc*scale[o]. AUXF32: residual fp32. OUTF32: Y fp32.
template <int AUXF32, int OUTF32>
__global__ __launch_bounds__(256, 2)
void gemm_k(const float* __restrict__ Wt, const u16* __restrict__ X,
            void* __restrict__ Yv, const void* __restrict__ aux,
            const float* __restrict__ scale, int M, int K, int xbatch)
{
  __shared__ __align__(16) u16 As[4][128][8];   // [kchunk][o][8]
  __shared__ __align__(16) u16 Bs[4][128][8];   // [kchunk][pixel][8]
  int mtiles = M >> 7;
  int mt = blockIdx.x % mtiles;
  int ntile = blockIdx.x / mtiles;
  int n0g = ntile << 7;
  int b = n0g >> 16;
  int p0 = n0g & (HW - 1);
  int o0 = mt << 7;
  const u16* Xb = X + (size_t)b * xbatch * HW;
  int t = threadIdx.x;
  int lane = t & 63, wv = t >> 6;
  int rb = (wv & 1) << 6, cb = (wv >> 1) << 6;
  int qd = lane >> 4, ln = lane & 15;
  f32x4 acc[4][4] = {};
  for (int c0 = 0; c0 < K; c0 += 32) {
#pragma unroll
    for (int it = 0; it < 2; ++it) {
      int tt = t + it * 256;
      int row = tt >> 2, ch = tt & 3;
      const float* wsrc = Wt + (size_t)(o0 + row) * K + c0 + ch * 8;
      uint4 pk;
      pk.x = (u32)f2bf(wsrc[0]) | ((u32)f2bf(wsrc[1]) << 16);
      pk.y = (u32)f2bf(wsrc[2]) | ((u32)f2bf(wsrc[3]) << 16);
      pk.z = (u32)f2bf(wsrc[4]) | ((u32)f2bf(wsrc[5]) << 16);
      pk.w = (u32)f2bf(wsrc[6]) | ((u32)f2bf(wsrc[7]) << 16);
      *(uint4*)&As[ch][row][0] = pk;
    }
    {
      int pp = (t & 63) << 1;
      int kc = t >> 6;
      const u16* src = Xb + (size_t)(c0 + kc * 8) * HW + p0 + pp;
      uint4 e, o;
      gatherB(src, e, o);
      *(uint4*)&Bs[kc][pp][0] = e;
      *(uint4*)&Bs[kc][pp + 1][0] = o;
    }
    __syncthreads();
    bf16x8 af[4], bfv[4];
#pragma unroll
    for (int i = 0; i < 4; ++i) {
      af[i] = *(const bf16x8*)&As[qd][rb + i * 16 + ln][0];
      bfv[i] = *(const bf16x8*)&Bs[qd][cb + i * 16 + ln][0];
    }
#pragma unroll
    for (int i = 0; i < 4; ++i)
#pragma unroll
      for (int j = 0; j < 4; ++j)
        acc[i][j] = __builtin_amdgcn_mfma_f32_16x16x32_bf16(af[i], bfv[j],
                                                            acc[i][j], 0, 0, 0);
    __syncthreads();
  }
  size_t ybase = (size_t)b * M * HW;
#pragma unroll
  for (int i = 0; i < 4; ++i) {
    int obase = o0 + rb + i * 16 + qd * 4;
#pragma unroll
    for (int j = 0; j < 4; ++j) {
      int p = p0 + cb + j * 16 + ln;
#pragma unroll
      for (int rr = 0; rr < 4; ++rr) {
        int o = obase + rr;
        size_t idx = ybase + (size_t)o * HW + p;
        float v = acc[i][j][rr];
        float r = AUXF32 ? ((const float*)aux)[idx]
                         : bf2f((u32)((const u16*)aux)[idx]);
        v = r + v * scale[o];
        if (OUTF32) ((float*)Yv)[idx] = v;
        else        ((u16*)Yv)[idx] = f2bf(v);
      }
    }
  }
}

// ---------------- folded conv1x1 GEMM, K=128: B-tile staged ONCE ------------
template <int EPI>
__global__ __launch_bounds__(256, 2)
void gemmf_k(const float* __restrict__ Wt, const u16* __restrict__ X,
             u16* __restrict__ Y, const float* __restrict__ bias,
             int MT, int xbatch)
{
  __shared__ __align__(16) u16 Bs[16][128][8];   // full-K B tile, 32 KB
  __shared__ __align__(16) u16 As[16][128][8];   // full-K A tile, 32 KB
  int n0g = blockIdx.x << 7;
  int b = n0g >> 16;
  int p0 = n0g & (HW - 1);
  const u16* Xb = X + (size_t)b * xbatch * HW;
  int t = threadIdx.x;
  int lane = t & 63, wv = t >> 6;
  int rb = (wv & 1) << 6, cb = (wv >> 1) << 6;
  int qd = lane >> 4, ln = lane & 15;
#pragma unroll
  for (int it = 0; it < 4; ++it) {
    int tt = t + it * 256;
    int pp = (tt & 63) << 1;
    int kc = tt >> 6;
    const u16* src = Xb + (size_t)(kc * 8) * HW + p0 + pp;
    uint4 e, o;
    gatherB(src, e, o);
    *(uint4*)&Bs[kc][pp][0] = e;
    *(uint4*)&Bs[kc][pp + 1][0] = o;
  }
  int M = MT << 7;
  size_t ybase = (size_t)b * M * HW;
  for (int mt = 0; mt < MT; ++mt) {
    int o0 = mt << 7;
    __syncthreads();   // prior tile's MFMA reads done (mt=0: B writes done)
#pragma unroll
    for (int it = 0; it < 8; ++it) {
      int tt = t + it * 256;
      int row = tt & 127, kc = tt >> 7;
      const float* wsrc = Wt + (size_t)(o0 + row) * 128 + kc * 8;
      float4 w0 = *(const float4*)wsrc;
      float4 w1 = *(const float4*)(wsrc + 4);
      uint4 pk;
      pk.x = (u32)f2bf(w0.x) | ((u32)f2bf(w0.y) << 16);
      pk.y = (u32)f2bf(w0.z) | ((u32)f2bf(w0.w) << 16);
      pk.z = (u32)f2bf(w1.x) | ((u32)f2bf(w1.y) << 16);
      pk.w = (u32)f2bf(w1.z) | ((u32)f2bf(w1.w) << 16);
      *(uint4*)&As[kc][row][0] = pk;
    }
    __syncthreads();
    f32x4 acc[4][4] = {};
#pragma unroll
    for (int s = 0; s < 4; ++s) {
      bf16x8 af[4], bfv[4];
#pragma unroll
      for (int i = 0; i < 4; ++i) {
        af[i] = *(const bf16x8*)&As[s * 4 + qd][rb + i * 16 + ln][0];
        bfv[i] = *(const bf16x8*)&Bs[s * 4 + qd][cb + i * 16 + ln][0];
      }
#pragma unroll
      for (int i = 0; i < 4; ++i)
#pragma unroll
        for (int j = 0; j < 4; ++j)
          acc[i][j] = __builtin_amdgcn_mfma_f32_16x16x32_bf16(af[i], bfv[j],
                                                              acc[i][j], 0, 0, 0);
    }
#pragma unroll
    for (int i = 0; i < 4; ++i) {
      int obase = o0 + rb + i * 16 + qd * 4;
#pragma unroll
      for (int j = 0; j < 4; ++j) {
        int p = p0 + cb + j * 16 + ln;
#pragma unroll
        for (int rr = 0; rr < 4; ++rr) {
          int o = obase + rr;
          float v = acc[i][j][rr];
          if (EPI == 1) v += bias[o];
          Y[ybase + (size_t)o * HW + p] = f2bf(v);
        }
      }
    }
  }
}

// ---------------- depthwise 3x3, SAME zero pad, IN-PLACE (bf16 data) --------
__device__ __forceinline__ void ldsrow(const u16* __restrict__ img, int h,
                                       int w0, float* r) {
  if ((unsigned)h > 255u) {
#pragma unroll
    for (int i = 0; i < 10; ++i) r[i] = 0.f;
    return;
  }
  const u16* rp = img + (h << 8) + w0;
  float c[8];
  unpack8(*(const uint4*)rp, c);
#pragma unroll
  for (int i = 0; i < 8; ++i) r[i + 1] = c[i];
  r[0] = (w0 > 0) ? bf2f((u32)rp[-1]) : 0.f;
  r[9] = (w0 < 248) ? bf2f((u32)rp[8]) : 0.f;
}

__global__ __launch_bounds__(1024)
void dwip_k(u16* __restrict__ buf, const float* __restrict__ wt, int C)
{
  __shared__ __align__(16) u16 img[65536];   // 128 KB: full channel
  int bc = blockIdx.x;                       // b*C + c
  int c = bc % C;
  size_t base = (size_t)bc << 16;
  int t = threadIdx.x;
  uint4* simg = (uint4*)img;
  const uint4* gsrc = (const uint4*)(buf + base);
#pragma unroll
  for (int it = 0; it < 8; ++it)
    simg[it * 1024 + t] = gsrc[it * 1024 + t];
  float wg[9];
#pragma unroll
  for (int i = 0; i < 9; ++i) wg[i] = wt[c * 9 + i];
  __syncthreads();
  uint4* gdst = (uint4*)(buf + base);
#pragma unroll
  for (int it = 0; it < 8; ++it) {
    int f = it * 1024 + t;
    int h = f >> 5;
    int w0 = (f & 31) << 3;
    float r0[10], r1[10], r2[10];
    ldsrow(img, h - 1, w0, r0);
    ldsrow(img, h,     w0, r1);
    ldsrow(img, h + 1, w0, r2);
    float o[8];
#pragma unroll
    for (int j = 0; j < 8; ++j) {
      float s = 0.f;
#pragma unroll
      for (int dx = 0; dx < 3; ++dx)
        s += r0[j + dx] * wg[dx] + r1[j + dx] * wg[3 + dx] +
             r2[j + dx] * wg[6 + dx];
      o[j] = s;
    }
    uint4 pk;
    pk.x = (u32)f2bf(o[0]) | ((u32)f2bf(o[1]) << 16);
    pk.y = (u32)f2bf(o[2]) | ((u32)f2bf(o[3]) << 16);
    pk.z = (u32)f2bf(o[4]) | ((u32)f2bf(o[5]) << 16);
    pk.w = (u32)f2bf(o[6]) | ((u32)f2bf(o[7]) << 16);
    gdst[f] = pk;   // global write; LDS still holds pristine input
  }
}

// ---------------- fused depthwise-3x3 + gate product (FFN tail) -------------
// block = (b, c in [0,128), half). Stage ch c half-channel (+halo rows) into
// 66.5 KB LDS, conv -> 32 regs; restage ch c+128, conv, multiply, store
// product to pr. NOT in-place, so half-channel tiling is race-free.
__device__ __forceinline__ void ldsrow2(const u16* __restrict__ img, int lr,
                                        int w0, float* r) {
  const u16* rp = img + (lr << 8) + w0;
  float c[8];
  unpack8(*(const uint4*)rp, c);
#pragma unroll
  for (int i = 0; i < 8; ++i) r[i + 1] = c[i];
  r[0] = (w0 > 0) ? bf2f((u32)rp[-1]) : 0.f;
  r[9] = (w0 < 248) ? bf2f((u32)rp[8]) : 0.f;
}

__global__ __launch_bounds__(1024)
void dwfuse_k(const u16* __restrict__ h4, const float* __restrict__ wt,
              u16* __restrict__ pr)
{
  __shared__ __align__(16) u16 img[33280];   // 130 rows x 256, 66.5 KB
  int bx = blockIdx.x;
  int b = bx >> 8;
  int c = (bx >> 1) & 127;
  int half = bx & 1;
  int h0 = half << 7;
  int t = threadIdx.x;
  float o1[32];
  size_t obase = ((size_t)((b << 7) + c) << 16);
#pragma unroll
  for (int pass = 0; pass < 2; ++pass) {
    int ch = c + pass * 128;
    size_t gbase = (size_t)((b << 8) + ch) << 16;
    __syncthreads();             // prior pass conv reads complete
    for (int idx = t; idx < 4160; idx += 1024) {
      int lr = idx >> 5, col = idx & 31;
      int gh = h0 - 1 + lr;
      uint4 v = {0, 0, 0, 0};
      if ((unsigned)gh < 256u)
        v = *(const uint4*)(h4 + gbase + ((size_t)gh << 8) + col * 8);
      *(uint4*)&img[(lr << 8) + col * 8] = v;
    }
    float wg[9];
#pragma unroll
    for (int i = 0; i < 9; ++i) wg[i] = wt[ch * 9 + i];
    __syncthreads();
#pragma unroll
    for (int it = 0; it < 4; ++it) {
      int f = it * 1024 + t;
      int lrr = f >> 5;            // 0..127 output row within half
      int w0 = (f & 31) << 3;
      float r0[10], r1[10], r2[10];
      ldsrow2(img, lrr,     w0, r0);  // global row h0+lrr-1
      ldsrow2(img, lrr + 1, w0, r1);
      ldsrow2(img, lrr + 2, w0, r2);
      float o[8];
#pragma unroll
      for (int j = 0; j < 8; ++j) {
        float s = 0.f;
#pragma unroll
        for (int dx = 0; dx < 3; ++dx)
          s += r0[j + dx] * wg[dx] + r1[j + dx] * wg[3 + dx] +
               r2[j + dx] * wg[6 + dx];
        o[j] = s;
      }
      if (pass == 0) {
#pragma unroll
        for (int j = 0; j < 8; ++j) o1[it * 8 + j] = o[j];
      } else {
        uint4 pk;
        pk.x = (u32)f2bf(o1[it*8+0] * o[0]) | ((u32)f2bf(o1[it*8+1] * o[1]) << 16);
        pk.y = (u32)f2bf(o1[it*8+2] * o[2]) | ((u32)f2bf(o1[it*8+3] * o[3]) << 16);
        pk.z = (u32)f2bf(o1[it*8+4] * o[4]) | ((u32)f2bf(o1[it*8+5] * o[5]) << 16);
        pk.w = (u32)f2bf(o1[it*8+6] * o[6]) | ((u32)f2bf(o1[it*8+7] * o[7]) << 16);
        *(uint4*)(pr + obase + ((size_t)(h0 + lrr) << 8) + w0) = pk;
      }
    }
  }
}

// ---------------- patch-FFT attention = 8x8 circular conv per patch/channel -
// v4: packed-bf16 v_dot2_f32_bf16, m-outer. q,k never unpacked: qp[i][t] as
// loaded; pk[r][n]=(k[r][n], k[r][n-1]) built with 1 op each. 2048 dot2 vs
// 4096 fma + ~2k unpack in v3. Live ~110 regs, no launch-bounds min (R4!).
// In-place over q-slot: q fully register-resident before first store.
__global__ __launch_bounds__(256)
void attn_k(u16* __restrict__ qkv)
{
  int wv = threadIdx.x >> 6, lane = threadIdx.x & 63;
  int task = blockIdx.x * 4 + wv;       // 8192 tasks: b(2) x c(256) x strip(16)
  int b = task >> 12;
  int c = (task >> 4) & 255;
  int strip = task & 15;
  int pr = lane >> 5, pw = lane & 31;
  int row = (strip << 4) + (pr << 3);   // patch top row
  size_t qbase = ((size_t)(b * 768 + c) << 16) + ((size_t)row << 8) + pw * 8;
  size_t kbase = qbase + ((size_t)256 << 16);
  u32 qp[8][4];
  u32 ku[8][4];
#pragma unroll
  for (int i = 0; i < 8; ++i) {
    uint4 qv = *(const uint4*)(qkv + qbase + (i << 8));
    uint4 kv = *(const uint4*)(qkv + kbase + (i << 8));
    qp[i][0] = qv.x; qp[i][1] = qv.y; qp[i][2] = qv.z; qp[i][3] = qv.w;
    ku[i][0] = kv.x; ku[i][1] = kv.y; ku[i][2] = kv.z; ku[i][3] = kv.w;
  }
  // pk[r][n] = pack(lo=k[r][n], hi=k[r][(n-1)&7])
  u32 pk[8][8];
#pragma unroll
  for (int r = 0; r < 8; ++r)
#pragma unroll
    for (int n = 0; n < 8; ++n) {
      if (n & 1) {
        u32 x = ku[r][n >> 1];
        pk[r][n] = (x >> 16) | (x << 16);
      } else {
        pk[r][n] = (ku[r][n >> 1] & 0xffffu) |
                   (ku[r][((n + 7) & 7) >> 1] & 0xffff0000u);
      }
    }
#pragma unroll
  for (int m = 0; m < 8; ++m) {
    float a[8] = {};
#pragma unroll
    for (int i = 0; i < 8; ++i) {
      const int r = (m - i) & 7;
#pragma unroll
      for (int t = 0; t < 4; ++t) {
        const u32 q = qp[i][t];
#pragma unroll
        for (int n = 0; n < 8; ++n)
          a[n] = dot2bf(q, pk[r][(n - 2 * t) & 7], a[n]);
      }
    }
    uint4 pko;
    pko.x = (u32)f2bf(a[0]) | ((u32)f2bf(a[1]) << 16);
    pko.y = (u32)f2bf(a[2]) | ((u32)f2bf(a[3]) << 16);
    pko.z = (u32)f2bf(a[4]) | ((u32)f2bf(a[5]) << 16);
    pko.w = (u32)f2bf(a[6]) | ((u32)f2bf(a[7]) << 16);
    *(uint4*)(qkv + qbase + (m << 8)) = pko;
  }
}

extern "C" void kernel_launch(void* const* d_in, const int* in_sizes, int n_in,
                              void* d_out, int out_size, void* d_ws, size_t ws_size,
                              hipStream_t stream)
{
  (void)in_sizes; (void)n_in; (void)out_size; (void)ws_size;
  const float* x    = (const float*)d_in[0];
  const float* n1w  = (const float*)d_in[1];
  const float* n1b  = (const float*)d_in[2];
  const float* wh1  = (const float*)d_in[3];
  const float* wdw1 = (const float*)d_in[4];
  const float* n2w  = (const float*)d_in[5];
  const float* n2b  = (const float*)d_in[6];
  const float* wp1  = (const float*)d_in[7];
  const float* n3w  = (const float*)d_in[8];
  const float* n3b  = (const float*)d_in[9];
  const float* wh2  = (const float*)d_in[10];
  const float* bh2  = (const float*)d_in[11];
  const float* wdw2 = (const float*)d_in[12];
  const float* wp2  = (const float*)d_in[13];
  const float* sc1  = (const float*)d_in[14];
  const float* sc2  = (const float*)d_in[15];
  float* out = (float*)d_out;
  u16* ws = (u16*)d_ws;

  // workspace (u16 elems), peak ~235 MB:
  //   A = ws          : (2,768,HW)  hidden -> qkv -> attn/va
  //                     later: h3 [0,16.7M) | h4 [16.7M,50.3M) | pr [0,16.7M)
  //   B = ws + 100.7M : (2,128,HW)  hln -> xmid (bf16)
  u16* A = ws;
  u16* B = ws + 100663296;
  u16* h3 = A;
  u16* h4 = A + 16777216;
  u16* pr = A;

  ln_k<1><<<256, 256, 0, stream>>>(x, n1w, n1b, B, 128);                     // hln
  gemmf_k<0><<<1024, 256, 0, stream>>>(wh1, B, A, nullptr, 6, 128);          // hidden
  dwip_k<<<1536, 1024, 0, stream>>>(A, wdw1, 768);                           // qkv
  attn_k<<<2048, 256, 0, stream>>>(A);                                       // attn -> q-slot
  ln2v_k<<<256, 256, 0, stream>>>(A, n2w, n2b);                              // va -> q-slot
  gemm_k<1,0><<<1024, 256, 0, stream>>>(wp1, A, B, x, sc1, 128, 256, 768);   // xmid -> B
  ln_k<0><<<256, 256, 0, stream>>>(B, n3w, n3b, h3, 128);
  gemmf_k<1><<<1024, 256, 0, stream>>>(wh2, h3, h4, bh2, 2, 128);            // h4
  dwfuse_k<<<512, 1024, 0, stream>>>(h4, wdw2, pr);                          // pr = g1*g2
  gemm_k<0,1><<<1024, 256, 0, stream>>>(wp2, pr, out, B, sc2, 128, 128, 128);
}